// Round 1
// baseline (1057.098 us; speedup 1.0000x reference)
//
#include <hip/hip_runtime.h>
#include <cstdint>
#include <cstddef>

#define N_TOK 8192
#define D_DIM 1024
#define H_DIM 4096
#define E_NUM 8
#define BM 128
#define BN 128
#define BK 32

typedef __bf16 bf16x8 __attribute__((ext_vector_type(8)));
typedef float floatx4 __attribute__((ext_vector_type(4)));
typedef unsigned short u16;

__device__ __forceinline__ u16 f2bf(float f) {
  unsigned int u = __float_as_uint(f);
  u += 0x7fff + ((u >> 16) & 1);   // RNE to bf16
  return (u16)(u >> 16);
}

__device__ __forceinline__ void gload_lds16(const void* g, void* l) {
  __builtin_amdgcn_global_load_lds((const __attribute__((address_space(1))) void*)g,
                                   (__attribute__((address_space(3))) void*)l, 16, 0, 0);
}

__global__ void init_k(int* __restrict__ cnt) {
  if (threadIdx.x < E_NUM) cnt[threadIdx.x] = 0;
}

__global__ __launch_bounds__(256) void cvt_k(const float* __restrict__ s, u16* __restrict__ d) {
  size_t i = (size_t)blockIdx.x * 256 + threadIdx.x;
  float4 v = ((const float4*)s)[i];
  ushort4 o;
  o.x = f2bf(v.x); o.y = f2bf(v.y); o.z = f2bf(v.z); o.w = f2bf(v.w);
  ((ushort4*)d)[i] = o;
}

// one wave per token: fp32 logits, top-2 + softmax, bucket scatter, out := w0*b2[e0]+w1*b2[e1]
__global__ __launch_bounds__(256) void gate_k(const float* __restrict__ x,
                                              const float* __restrict__ Wg,
                                              const float* __restrict__ b2,
                                              float* __restrict__ out,
                                              int* __restrict__ cnt,
                                              int* __restrict__ rows,
                                              float* __restrict__ wrow) {
  int tid = threadIdx.x;
  int wv = tid >> 6, lane = tid & 63;
  int n = blockIdx.x * 4 + wv;
  const float* xr = x + (size_t)n * D_DIM;
  float acc[E_NUM];
#pragma unroll
  for (int e = 0; e < E_NUM; e++) acc[e] = 0.f;
#pragma unroll
  for (int q = 0; q < 4; q++) {
    int d = q * 256 + lane * 4;
    float4 xv = *(const float4*)(xr + d);
#pragma unroll
    for (int e = 0; e < E_NUM; e++) {
      float4 w4 = *(const float4*)(Wg + (size_t)e * D_DIM + d);
      acc[e] += xv.x * w4.x + xv.y * w4.y + xv.z * w4.z + xv.w * w4.w;
    }
  }
#pragma unroll
  for (int e = 0; e < E_NUM; e++) {
#pragma unroll
    for (int off = 32; off >= 1; off >>= 1) acc[e] += __shfl_xor(acc[e], off, 64);
  }
  // top-2, ties -> lower index (matches lax.top_k)
  int e0 = 0; float v0 = acc[0];
#pragma unroll
  for (int e = 1; e < E_NUM; e++) if (acc[e] > v0) { v0 = acc[e]; e0 = e; }
  int e1 = (e0 == 0) ? 1 : 0; float v1 = acc[e1];
#pragma unroll
  for (int e = 0; e < E_NUM; e++) if (e != e0 && acc[e] > v1) { v1 = acc[e]; e1 = e; }
  float p1 = expf(v1 - v0);
  float w0 = 1.f / (1.f + p1);
  float w1 = p1 / (1.f + p1);
  const float* b2a = b2 + (size_t)e0 * D_DIM;
  const float* b2b = b2 + (size_t)e1 * D_DIM;
  float* orow = out + (size_t)n * D_DIM;
#pragma unroll
  for (int q = 0; q < 4; q++) {
    int d = q * 256 + lane * 4;
    float4 a4 = *(const float4*)(b2a + d);
    float4 c4 = *(const float4*)(b2b + d);
    float4 o;
    o.x = w0 * a4.x + w1 * c4.x;
    o.y = w0 * a4.y + w1 * c4.y;
    o.z = w0 * a4.z + w1 * c4.z;
    o.w = w0 * a4.w + w1 * c4.w;
    *(float4*)(orow + d) = o;
  }
  if (lane == 0) {
    int p = atomicAdd(&cnt[e0], 1);
    rows[e0 * N_TOK + p] = n * 2;
    p = atomicAdd(&cnt[e1], 1);
    rows[e1 * N_TOK + p] = n * 2 + 1;
    wrow[n * 2] = w0;
    wrow[n * 2 + 1] = w1;
  }
}

// grouped GEMM: h[row] = gelu(x[token] . W1[e]^T + b1[e]), bf16 out
__global__ __launch_bounds__(256) void fc1_k(const u16* __restrict__ xbf,
                                             const u16* __restrict__ w1bf,
                                             const float* __restrict__ b1,
                                             u16* __restrict__ hbf,
                                             const int* __restrict__ cnt,
                                             const int* __restrict__ rows) {
  int bx = blockIdx.x;
  int e = bx >> 11;          // 2048 blocks/expert = 64 m-tiles * 32 n-tiles
  int t = bx & 2047;
  int m0 = (t >> 5) * BM;
  int n0 = (t & 31) * BN;
  int ce = cnt[e];
  if (m0 >= ce) return;

  __shared__ __align__(16) u16 As[BM * BK];
  __shared__ __align__(16) u16 Bs[BN * BK];
  __shared__ int rows_s[BM];

  int tid = threadIdx.x;
  int wv = tid >> 6, lane = tid & 63;
  const int* erows = rows + e * N_TOK;
  if (tid < BM) {
    int p = m0 + tid;
    rows_s[tid] = (p < ce) ? erows[p] : 0;
  }
  int r4 = tid >> 2;
  int cb = (tid & 3) * 16;
  int pa0 = m0 + r4, pa1 = m0 + 64 + r4;
  int rid0 = (pa0 < ce) ? erows[pa0] : 0;
  int rid1 = (pa1 < ce) ? erows[pa1] : 0;
  const char* aptr0 = (const char*)(xbf + (size_t)(rid0 >> 1) * D_DIM) + cb;
  const char* aptr1 = (const char*)(xbf + (size_t)(rid1 >> 1) * D_DIM) + cb;
  const char* bptr = (const char*)(w1bf + ((size_t)e * H_DIM + n0 + r4) * D_DIM) + cb;
  u16* As_w = As + wv * 512;
  u16* Bs_w = Bs + wv * 512;

  floatx4 zero = {0.f, 0.f, 0.f, 0.f};
  floatx4 acc[4][4];
#pragma unroll
  for (int i = 0; i < 4; i++)
#pragma unroll
    for (int j = 0; j < 4; j++) acc[i][j] = zero;

  int wm = (wv >> 1) * 64;
  int wn = (wv & 1) * 64;
  int lrow = lane & 15;
  int lko = (lane >> 4) * 8;

  for (int kk = 0; kk < D_DIM / BK; kk++) {
    size_t koff = (size_t)kk * (BK * 2);
    __syncthreads();
    gload_lds16(aptr0 + koff, As_w);
    gload_lds16(aptr1 + koff, As_w + 2048);
    gload_lds16(bptr + koff, Bs_w);
    gload_lds16(bptr + (size_t)64 * D_DIM * 2 + koff, Bs_w + 2048);
    __syncthreads();
    bf16x8 a[4], b[4];
#pragma unroll
    for (int i = 0; i < 4; i++) a[i] = *(const bf16x8*)&As[(wm + i * 16 + lrow) * BK + lko];
#pragma unroll
    for (int j = 0; j < 4; j++) b[j] = *(const bf16x8*)&Bs[(wn + j * 16 + lrow) * BK + lko];
#pragma unroll
    for (int i = 0; i < 4; i++)
#pragma unroll
      for (int j = 0; j < 4; j++)
        acc[i][j] = __builtin_amdgcn_mfma_f32_16x16x32_bf16(a[i], b[j], acc[i][j], 0, 0, 0);
  }

  const float* b1e = b1 + (size_t)e * H_DIM + n0;
#pragma unroll
  for (int i = 0; i < 4; i++) {
#pragma unroll
    for (int j = 0; j < 4; j++) {
#pragma unroll
      for (int r = 0; r < 4; r++) {
        int ml = wm + i * 16 + (lane >> 4) * 4 + r;
        int nl = wn + j * 16 + (lane & 15);
        int p = m0 + ml;
        if (p < ce) {
          float v = acc[i][j][r] + b1e[nl];
          v = 0.5f * v * (1.0f + erff(v * 0.70710678118654752f));
          hbf[(size_t)rows_s[ml] * H_DIM + n0 + nl] = f2bf(v);
        }
      }
    }
  }
}

// grouped GEMM: out[token] += w_row * (h[row] . W2[e]^T)
__global__ __launch_bounds__(256) void fc2_k(const u16* __restrict__ hbf,
                                             const u16* __restrict__ w2bf,
                                             float* __restrict__ out,
                                             const int* __restrict__ cnt,
                                             const int* __restrict__ rows,
                                             const float* __restrict__ wrow) {
  int bx = blockIdx.x;
  int e = bx >> 9;           // 512 blocks/expert = 64 m-tiles * 8 n-tiles
  int t = bx & 511;
  int m0 = (t >> 3) * BM;
  int n0 = (t & 7) * BN;
  int ce = cnt[e];
  if (m0 >= ce) return;

  __shared__ __align__(16) u16 As[BM * BK];
  __shared__ __align__(16) u16 Bs[BN * BK];
  __shared__ int rows_s[BM];
  __shared__ float w_s[BM];

  int tid = threadIdx.x;
  int wv = tid >> 6, lane = tid & 63;
  const int* erows = rows + e * N_TOK;
  if (tid < BM) {
    int p = m0 + tid;
    int rid = (p < ce) ? erows[p] : 0;
    rows_s[tid] = rid;
    w_s[tid] = (p < ce) ? wrow[rid] : 0.f;
  }
  int r4 = tid >> 2;
  int cb = (tid & 3) * 16;
  int pa0 = m0 + r4, pa1 = m0 + 64 + r4;
  int rid0 = (pa0 < ce) ? erows[pa0] : 0;
  int rid1 = (pa1 < ce) ? erows[pa1] : 0;
  const char* aptr0 = (const char*)(hbf + (size_t)rid0 * H_DIM) + cb;
  const char* aptr1 = (const char*)(hbf + (size_t)rid1 * H_DIM) + cb;
  const char* bptr = (const char*)(w2bf + ((size_t)e * D_DIM + n0 + r4) * H_DIM) + cb;
  u16* As_w = As + wv * 512;
  u16* Bs_w = Bs + wv * 512;

  floatx4 zero = {0.f, 0.f, 0.f, 0.f};
  floatx4 acc[4][4];
#pragma unroll
  for (int i = 0; i < 4; i++)
#pragma unroll
    for (int j = 0; j < 4; j++) acc[i][j] = zero;

  int wm = (wv >> 1) * 64;
  int wn = (wv & 1) * 64;
  int lrow = lane & 15;
  int lko = (lane >> 4) * 8;

  for (int kk = 0; kk < H_DIM / BK; kk++) {
    size_t koff = (size_t)kk * (BK * 2);
    __syncthreads();
    gload_lds16(aptr0 + koff, As_w);
    gload_lds16(aptr1 + koff, As_w + 2048);
    gload_lds16(bptr + koff, Bs_w);
    gload_lds16(bptr + (size_t)64 * H_DIM * 2 + koff, Bs_w + 2048);
    __syncthreads();
    bf16x8 a[4], b[4];
#pragma unroll
    for (int i = 0; i < 4; i++) a[i] = *(const bf16x8*)&As[(wm + i * 16 + lrow) * BK + lko];
#pragma unroll
    for (int j = 0; j < 4; j++) b[j] = *(const bf16x8*)&Bs[(wn + j * 16 + lrow) * BK + lko];
#pragma unroll
    for (int i = 0; i < 4; i++)
#pragma unroll
      for (int j = 0; j < 4; j++)
        acc[i][j] = __builtin_amdgcn_mfma_f32_16x16x32_bf16(a[i], b[j], acc[i][j], 0, 0, 0);
  }

#pragma unroll
  for (int i = 0; i < 4; i++) {
#pragma unroll
    for (int j = 0; j < 4; j++) {
#pragma unroll
      for (int r = 0; r < 4; r++) {
        int ml = wm + i * 16 + (lane >> 4) * 4 + r;
        int nl = wn + j * 16 + (lane & 15);
        int p = m0 + ml;
        if (p < ce) {
          float v = acc[i][j][r] * w_s[ml];
          unsafeAtomicAdd(&out[(size_t)(rows_s[ml] >> 1) * D_DIM + n0 + nl], v);
        }
      }
    }
  }
}

extern "C" void kernel_launch(void* const* d_in, const int* in_sizes, int n_in,
                              void* d_out, int out_size, void* d_ws, size_t ws_size,
                              hipStream_t stream) {
  const float* x  = (const float*)d_in[0];
  const float* Wg = (const float*)d_in[1];
  const float* W1 = (const float*)d_in[2];
  const float* b1 = (const float*)d_in[3];
  const float* W2 = (const float*)d_in[4];
  const float* b2 = (const float*)d_in[5];
  float* out = (float*)d_out;

  char* ws = (char*)d_ws;
  size_t off = 0;
  auto alloc = [&](size_t bytes) -> void* {
    void* p = ws + off;
    off += (bytes + 255) & ~(size_t)255;
    return p;
  };
  int*   cnt  = (int*)alloc(E_NUM * sizeof(int));
  int*   rows = (int*)alloc((size_t)E_NUM * N_TOK * sizeof(int));
  float* wrow = (float*)alloc((size_t)N_TOK * 2 * sizeof(float));
  u16*   xbf  = (u16*)alloc((size_t)N_TOK * D_DIM * 2);
  u16*   w1bf = (u16*)alloc((size_t)E_NUM * H_DIM * D_DIM * 2);
  u16*   w2bf = (u16*)alloc((size_t)E_NUM * D_DIM * H_DIM * 2);
  u16*   hbf  = (u16*)alloc((size_t)N_TOK * 2 * H_DIM * 2);
  if (off > ws_size) return;  // diagnostic: absmax == max|ref| with no crash => ws too small

  init_k<<<1, 64, 0, stream>>>(cnt);
  cvt_k<<<(N_TOK * D_DIM) / 1024, 256, 0, stream>>>(x, xbf);
  cvt_k<<<(E_NUM * H_DIM * D_DIM) / 1024, 256, 0, stream>>>(W1, w1bf);
  cvt_k<<<(E_NUM * D_DIM * H_DIM) / 1024, 256, 0, stream>>>(W2, w2bf);
  gate_k<<<N_TOK / 4, 256, 0, stream>>>(x, Wg, b2, out, cnt, rows, wrow);
  fc1_k<<<E_NUM * 64 * 32, 256, 0, stream>>>(xbf, w1bf, b1, hbf, cnt, rows);
  fc2_k<<<E_NUM * 64 * 8, 256, 0, stream>>>(hbf, w2bf, out, cnt, rows, wrow);
}

// Round 2
// 959.248 us; speedup vs baseline: 1.1020x; 1.1020x over previous
//
#include <hip/hip_runtime.h>
#include <cstdint>
#include <cstddef>

#define N_TOK 8192
#define D_DIM 1024
#define H_DIM 4096
#define E_NUM 8
#define BM 128
#define BN 128
#define BK 32

typedef __bf16 bf16x8 __attribute__((ext_vector_type(8)));
typedef float floatx4 __attribute__((ext_vector_type(4)));
typedef unsigned short u16;

__device__ __forceinline__ u16 f2bf(float f) {
  unsigned int u = __float_as_uint(f);
  u += 0x7fff + ((u >> 16) & 1);   // RNE to bf16
  return (u16)(u >> 16);
}

// gelu tanh-form via sigmoid: v / (1 + exp(-2y)), y = v*(c1 + c2*v^2)
__device__ __forceinline__ float gelu_f(float v) {
  float y = v * (0.7978845608f + 0.0356774081f * v * v);
  return v / (1.0f + __expf(-2.0f * y));
}

__device__ __forceinline__ void gload_lds16(const void* g, void* l) {
  __builtin_amdgcn_global_load_lds((const __attribute__((address_space(1))) void*)g,
                                   (__attribute__((address_space(3))) void*)l, 16, 0, 0);
}

__global__ void init_k(int* __restrict__ cnt) {
  if (threadIdx.x < E_NUM) cnt[threadIdx.x] = 0;
}

__global__ __launch_bounds__(256) void cvt_k(const float* __restrict__ s, u16* __restrict__ d) {
  size_t i = (size_t)blockIdx.x * 256 + threadIdx.x;
  float4 v = ((const float4*)s)[i];
  ushort4 o;
  o.x = f2bf(v.x); o.y = f2bf(v.y); o.z = f2bf(v.z); o.w = f2bf(v.w);
  ((ushort4*)d)[i] = o;
}

// one wave per token: fp32 logits, top-2 + softmax, bucket scatter,
// out := w0*b2[e0]+w1*b2[e1], and fused x -> bf16 conversion
__global__ __launch_bounds__(256) void gate_k(const float* __restrict__ x,
                                              const float* __restrict__ Wg,
                                              const float* __restrict__ b2,
                                              float* __restrict__ out,
                                              int* __restrict__ cnt,
                                              int* __restrict__ rows,
                                              float* __restrict__ wrow,
                                              u16* __restrict__ xbf) {
  int tid = threadIdx.x;
  int wv = tid >> 6, lane = tid & 63;
  int n = blockIdx.x * 4 + wv;
  const float* xr = x + (size_t)n * D_DIM;
  float acc[E_NUM];
#pragma unroll
  for (int e = 0; e < E_NUM; e++) acc[e] = 0.f;
#pragma unroll
  for (int q = 0; q < 4; q++) {
    int d = q * 256 + lane * 4;
    float4 xv = *(const float4*)(xr + d);
    ushort4 xo;
    xo.x = f2bf(xv.x); xo.y = f2bf(xv.y); xo.z = f2bf(xv.z); xo.w = f2bf(xv.w);
    *(ushort4*)(xbf + (size_t)n * D_DIM + d) = xo;
#pragma unroll
    for (int e = 0; e < E_NUM; e++) {
      float4 w4 = *(const float4*)(Wg + (size_t)e * D_DIM + d);
      acc[e] += xv.x * w4.x + xv.y * w4.y + xv.z * w4.z + xv.w * w4.w;
    }
  }
#pragma unroll
  for (int e = 0; e < E_NUM; e++) {
#pragma unroll
    for (int off = 32; off >= 1; off >>= 1) acc[e] += __shfl_xor(acc[e], off, 64);
  }
  // top-2, ties -> lower index (matches lax.top_k)
  int e0 = 0; float v0 = acc[0];
#pragma unroll
  for (int e = 1; e < E_NUM; e++) if (acc[e] > v0) { v0 = acc[e]; e0 = e; }
  int e1 = (e0 == 0) ? 1 : 0; float v1 = acc[e1];
#pragma unroll
  for (int e = 0; e < E_NUM; e++) if (e != e0 && acc[e] > v1) { v1 = acc[e]; e1 = e; }
  float p1 = expf(v1 - v0);
  float w0 = 1.f / (1.f + p1);
  float w1 = p1 / (1.f + p1);
  const float* b2a = b2 + (size_t)e0 * D_DIM;
  const float* b2b = b2 + (size_t)e1 * D_DIM;
  float* orow = out + (size_t)n * D_DIM;
#pragma unroll
  for (int q = 0; q < 4; q++) {
    int d = q * 256 + lane * 4;
    float4 a4 = *(const float4*)(b2a + d);
    float4 c4 = *(const float4*)(b2b + d);
    float4 o;
    o.x = w0 * a4.x + w1 * c4.x;
    o.y = w0 * a4.y + w1 * c4.y;
    o.z = w0 * a4.z + w1 * c4.z;
    o.w = w0 * a4.w + w1 * c4.w;
    *(float4*)(orow + d) = o;
  }
  if (lane == 0) {
    int p = atomicAdd(&cnt[e0], 1);
    rows[e0 * N_TOK + p] = n * 2;
    p = atomicAdd(&cnt[e1], 1);
    rows[e1 * N_TOK + p] = n * 2 + 1;
    wrow[n * 2] = w0;
    wrow[n * 2 + 1] = w1;
  }
}

// grouped GEMM: h[row] = gelu(x[token] . W1[e]^T + b1[e]), bf16 out
// LDS k-chunk XOR swizzle: global chunk (c ^ ((row>>1)&3)) stored at lds chunk c
__global__ __launch_bounds__(256) void fc1_k(const u16* __restrict__ xbf,
                                             const u16* __restrict__ w1bf,
                                             const float* __restrict__ b1,
                                             u16* __restrict__ hbf,
                                             const int* __restrict__ cnt,
                                             const int* __restrict__ rows) {
  int bx = blockIdx.x;
  int e = bx >> 11;          // 2048 blocks/expert = 64 m-tiles * 32 n-tiles
  int t = bx & 2047;
  int m0 = (t >> 5) * BM;
  int n0 = (t & 31) * BN;
  int ce = cnt[e];
  if (m0 >= ce) return;

  __shared__ __align__(16) u16 As[BM * BK];
  __shared__ __align__(16) u16 Bs[BN * BK];
  __shared__ int rows_s[BM];

  int tid = threadIdx.x;
  int wv = tid >> 6, lane = tid & 63;
  const int* erows = rows + e * N_TOK;
  if (tid < BM) {
    int p = m0 + tid;
    rows_s[tid] = (p < ce) ? erows[p] : 0;
  }
  int r4 = tid >> 2;
  int cb = ((tid & 3) ^ ((r4 >> 1) & 3)) * 16;   // swizzled source k-chunk (bytes)
  int pa0 = m0 + r4, pa1 = m0 + 64 + r4;
  int rid0 = (pa0 < ce) ? erows[pa0] : 0;
  int rid1 = (pa1 < ce) ? erows[pa1] : 0;
  const char* aptr0 = (const char*)(xbf + (size_t)(rid0 >> 1) * D_DIM) + cb;
  const char* aptr1 = (const char*)(xbf + (size_t)(rid1 >> 1) * D_DIM) + cb;
  const char* bptr = (const char*)(w1bf + ((size_t)e * H_DIM + n0 + r4) * D_DIM) + cb;
  u16* As_w = As + wv * 512;
  u16* Bs_w = Bs + wv * 512;

  floatx4 zero = {0.f, 0.f, 0.f, 0.f};
  floatx4 acc[4][4];
#pragma unroll
  for (int i = 0; i < 4; i++)
#pragma unroll
    for (int j = 0; j < 4; j++) acc[i][j] = zero;

  int wm = (wv >> 1) * 64;
  int wn = (wv & 1) * 64;
  int lrow = lane & 15;
  int lko = ((lane >> 4) ^ ((lrow >> 1) & 3)) * 8;   // swizzled read k-offset (elems)

  for (int kk = 0; kk < D_DIM / BK; kk++) {
    size_t koff = (size_t)kk * (BK * 2);
    __syncthreads();
    gload_lds16(aptr0 + koff, As_w);
    gload_lds16(aptr1 + koff, As_w + 2048);
    gload_lds16(bptr + koff, Bs_w);
    gload_lds16(bptr + (size_t)64 * D_DIM * 2 + koff, Bs_w + 2048);
    __syncthreads();
    bf16x8 a[4], b[4];
#pragma unroll
    for (int i = 0; i < 4; i++) a[i] = *(const bf16x8*)&As[(wm + i * 16 + lrow) * BK + lko];
#pragma unroll
    for (int j = 0; j < 4; j++) b[j] = *(const bf16x8*)&Bs[(wn + j * 16 + lrow) * BK + lko];
#pragma unroll
    for (int i = 0; i < 4; i++)
#pragma unroll
      for (int j = 0; j < 4; j++)
        acc[i][j] = __builtin_amdgcn_mfma_f32_16x16x32_bf16(a[i], b[j], acc[i][j], 0, 0, 0);
  }

  const float* b1e = b1 + (size_t)e * H_DIM + n0;
  float bias[4];
#pragma unroll
  for (int j = 0; j < 4; j++) bias[j] = b1e[wn + j * 16 + (lane & 15)];
#pragma unroll
  for (int i = 0; i < 4; i++) {
    int mlb = wm + i * 16 + (lane >> 4) * 4;
#pragma unroll
    for (int r = 0; r < 4; r++) {
      int ml = mlb + r;
      if (m0 + ml < ce) {
        size_t rowoff = (size_t)rows_s[ml] * H_DIM + n0 + wn + (lane & 15);
#pragma unroll
        for (int j = 0; j < 4; j++) {
          float v = acc[i][j][r] + bias[j];
          hbf[rowoff + j * 16] = f2bf(gelu_f(v));
        }
      }
    }
  }
}

// grouped GEMM: out[token] += w_row * (h[row] . W2[e]^T)
__global__ __launch_bounds__(256) void fc2_k(const u16* __restrict__ hbf,
                                             const u16* __restrict__ w2bf,
                                             float* __restrict__ out,
                                             const int* __restrict__ cnt,
                                             const int* __restrict__ rows,
                                             const float* __restrict__ wrow) {
  int bx = blockIdx.x;
  int e = bx >> 9;           // 512 blocks/expert = 64 m-tiles * 8 n-tiles
  int t = bx & 511;
  int m0 = (t >> 3) * BM;
  int n0 = (t & 7) * BN;
  int ce = cnt[e];
  if (m0 >= ce) return;

  __shared__ __align__(16) u16 As[BM * BK];
  __shared__ __align__(16) u16 Bs[BN * BK];
  __shared__ int rows_s[BM];
  __shared__ float w_s[BM];

  int tid = threadIdx.x;
  int wv = tid >> 6, lane = tid & 63;
  const int* erows = rows + e * N_TOK;
  if (tid < BM) {
    int p = m0 + tid;
    int rid = (p < ce) ? erows[p] : 0;
    rows_s[tid] = rid;
    w_s[tid] = (p < ce) ? wrow[rid] : 0.f;
  }
  int r4 = tid >> 2;
  int cb = ((tid & 3) ^ ((r4 >> 1) & 3)) * 16;   // swizzled source k-chunk (bytes)
  int pa0 = m0 + r4, pa1 = m0 + 64 + r4;
  int rid0 = (pa0 < ce) ? erows[pa0] : 0;
  int rid1 = (pa1 < ce) ? erows[pa1] : 0;
  const char* aptr0 = (const char*)(hbf + (size_t)rid0 * H_DIM) + cb;
  const char* aptr1 = (const char*)(hbf + (size_t)rid1 * H_DIM) + cb;
  const char* bptr = (const char*)(w2bf + ((size_t)e * D_DIM + n0 + r4) * H_DIM) + cb;
  u16* As_w = As + wv * 512;
  u16* Bs_w = Bs + wv * 512;

  floatx4 zero = {0.f, 0.f, 0.f, 0.f};
  floatx4 acc[4][4];
#pragma unroll
  for (int i = 0; i < 4; i++)
#pragma unroll
    for (int j = 0; j < 4; j++) acc[i][j] = zero;

  int wm = (wv >> 1) * 64;
  int wn = (wv & 1) * 64;
  int lrow = lane & 15;
  int lko = ((lane >> 4) ^ ((lrow >> 1) & 3)) * 8;   // swizzled read k-offset (elems)

  for (int kk = 0; kk < H_DIM / BK; kk++) {
    size_t koff = (size_t)kk * (BK * 2);
    __syncthreads();
    gload_lds16(aptr0 + koff, As_w);
    gload_lds16(aptr1 + koff, As_w + 2048);
    gload_lds16(bptr + koff, Bs_w);
    gload_lds16(bptr + (size_t)64 * H_DIM * 2 + koff, Bs_w + 2048);
    __syncthreads();
    bf16x8 a[4], b[4];
#pragma unroll
    for (int i = 0; i < 4; i++) a[i] = *(const bf16x8*)&As[(wm + i * 16 + lrow) * BK + lko];
#pragma unroll
    for (int j = 0; j < 4; j++) b[j] = *(const bf16x8*)&Bs[(wn + j * 16 + lrow) * BK + lko];
#pragma unroll
    for (int i = 0; i < 4; i++)
#pragma unroll
      for (int j = 0; j < 4; j++)
        acc[i][j] = __builtin_amdgcn_mfma_f32_16x16x32_bf16(a[i], b[j], acc[i][j], 0, 0, 0);
  }

#pragma unroll
  for (int i = 0; i < 4; i++) {
    int mlb = wm + i * 16 + (lane >> 4) * 4;
#pragma unroll
    for (int r = 0; r < 4; r++) {
      int ml = mlb + r;
      if (m0 + ml < ce) {
        float wsc = w_s[ml];
        float* orow = out + (size_t)(rows_s[ml] >> 1) * D_DIM + n0 + wn + (lane & 15);
#pragma unroll
        for (int j = 0; j < 4; j++) {
          unsafeAtomicAdd(&orow[j * 16], acc[i][j][r] * wsc);
        }
      }
    }
  }
}

extern "C" void kernel_launch(void* const* d_in, const int* in_sizes, int n_in,
                              void* d_out, int out_size, void* d_ws, size_t ws_size,
                              hipStream_t stream) {
  const float* x  = (const float*)d_in[0];
  const float* Wg = (const float*)d_in[1];
  const float* W1 = (const float*)d_in[2];
  const float* b1 = (const float*)d_in[3];
  const float* W2 = (const float*)d_in[4];
  const float* b2 = (const float*)d_in[5];
  float* out = (float*)d_out;

  char* ws = (char*)d_ws;
  size_t off = 0;
  auto alloc = [&](size_t bytes) -> void* {
    void* p = ws + off;
    off += (bytes + 255) & ~(size_t)255;
    return p;
  };
  int*   cnt  = (int*)alloc(E_NUM * sizeof(int));
  int*   rows = (int*)alloc((size_t)E_NUM * N_TOK * sizeof(int));
  float* wrow = (float*)alloc((size_t)N_TOK * 2 * sizeof(float));
  u16*   xbf  = (u16*)alloc((size_t)N_TOK * D_DIM * 2);
  u16*   w1bf = (u16*)alloc((size_t)E_NUM * H_DIM * D_DIM * 2);
  u16*   w2bf = (u16*)alloc((size_t)E_NUM * D_DIM * H_DIM * 2);
  u16*   hbf  = (u16*)alloc((size_t)N_TOK * 2 * H_DIM * 2);
  if (off > ws_size) return;  // diagnostic: absmax == max|ref| with no crash => ws too small

  init_k<<<1, 64, 0, stream>>>(cnt);
  cvt_k<<<(E_NUM * H_DIM * D_DIM) / 1024, 256, 0, stream>>>(W1, w1bf);
  cvt_k<<<(E_NUM * D_DIM * H_DIM) / 1024, 256, 0, stream>>>(W2, w2bf);
  gate_k<<<N_TOK / 4, 256, 0, stream>>>(x, Wg, b2, out, cnt, rows, wrow, xbf);
  fc1_k<<<E_NUM * 64 * 32, 256, 0, stream>>>(xbf, w1bf, b1, hbf, cnt, rows);
  fc2_k<<<E_NUM * 64 * 8, 256, 0, stream>>>(hbf, w2bf, out, cnt, rows, wrow);
}